// Round 7
// baseline (364.140 us; speedup 1.0000x reference)
//
#include <hip/hip_runtime.h>
#include <hip/hip_bf16.h>
#include <math.h>

// Attention block: y = out_proj(causal_softmax(rope(q)·rope(k)^T)·v)
// B=2 T=2048 C=2048 Hq=32 Hkv=8 D=64. bf16 MFMA, fp32 accumulate.
// R12: attn drops ALL LDS staging (m169 lesson: staging L2-fit data is pure
// overhead). K and V fragments are loaded straight from global: per-tile
// working set (8KB K + 8KB V) fits L1, cross-wave re-reads are L1 hits.
// Kernel is now barrier-free; waves are independent and the compiler can
// hoist next-tile loads. Bijective chunk remap wid=(lin&7)*64+lin>>3 puts
// 8 consecutive heads (= 2 KV pairs = 1MB) per XCD for L2 locality.
// 2-pass (qt,15-qt) pairing kept (constant work per block = robust balance;
// R6's co-resident-reflection regressed due to dispatch assumptions).
// GEMMs unchanged (XCD-swizzled 128x128; 2.58 TF/CU wall stands).

typedef __attribute__((ext_vector_type(8))) short short8;
typedef __attribute__((ext_vector_type(4))) float f32x4;
typedef __attribute__((ext_vector_type(16))) float f32x16;
typedef __attribute__((ext_vector_type(2))) unsigned int uint2v;

#define MFMA16(a,b,c) __builtin_amdgcn_mfma_f32_16x16x32_bf16((a),(b),(c),0,0,0)
#define MFMA32(a,b,c) __builtin_amdgcn_mfma_f32_32x32x16_bf16((a),(b),(c),0,0,0)
#define QSCALE 0.18033688011112043f   // (1/sqrt(64))*log2(e): exp2-domain softmax
#define NFREQ  (-13.28771237954945f / 32.0f)  // -log2(10000)/32

__device__ __forceinline__ ushort f2bf(float f) {
  union { float f; unsigned u; } x; x.f = f;
  unsigned r = x.u + 0x7fffu + ((x.u >> 16) & 1u);   // RNE
  return (ushort)(r >> 16);
}
// round-half-up packed bf16 pair (5 int ops)
__device__ __forceinline__ uint pkbf(float a, float b) {
  union { float f; unsigned u; } x, y; x.f = a; y.f = b;
  return ((x.u + 0x8000u) >> 16) | ((y.u + 0x8000u) & 0xffff0000u);
}

__device__ __forceinline__ void g2l16(const void* g, void* l) {
  __builtin_amdgcn_global_load_lds(
      (__attribute__((address_space(1))) void*)g,
      (__attribute__((address_space(3))) void*)l, 16, 0, 0);
}

// one kernel for all fp32->bf16 conversions
__global__ void cvt_all(const float* __restrict__ x,  const float* __restrict__ wq,
                        const float* __restrict__ wk, const float* __restrict__ wv,
                        const float* __restrict__ wo,
                        ushort* __restrict__ x_bf, ushort* __restrict__ wqkv,
                        ushort* __restrict__ wo_bf) {
  int i = blockIdx.x * 256 + threadIdx.x;
  const float4* src; ushort* dst; int off;
  if (i < 2097152)      { src = (const float4*)x;  dst = x_bf;             off = i; }
  else if (i < 3145728) { src = (const float4*)wq; dst = wqkv;             off = i - 2097152; }
  else if (i < 3407872) { src = (const float4*)wk; dst = wqkv + 4194304;   off = i - 3145728; }
  else if (i < 3670016) { src = (const float4*)wv; dst = wqkv + 5242880;   off = i - 3407872; }
  else                  { src = (const float4*)wo; dst = wo_bf;            off = i - 3670016; }
  float4 v = src[off];
  ushort4 o;
  o.x = f2bf(v.x); o.y = f2bf(v.y); o.z = f2bf(v.z); o.w = f2bf(v.w);
  ((ushort4*)dst)[off] = o;
}

// QKV GEMM with fused RoPE/scatter epilogue. M=4096, N=3072, K=2048,
// grid (24,32) remapped so each XCD computes 96 contiguous tiles (4 y-rows):
// A-panels stay L2-local per XCD. Col-segment (swizzled bx): bx<16 -> q
// (rope+QSCALE -> qr), 16..19 -> k (rope -> kr), 20..23 -> v (-> vt).
__global__ __launch_bounds__(256, 3)
void gemm_qkv(const ushort* __restrict__ A, const ushort* __restrict__ Bw,
              const float* __restrict__ bq, const float* __restrict__ bk,
              const float* __restrict__ bv,
              ushort* __restrict__ qr, ushort* __restrict__ kr,
              ushort* __restrict__ vt) {
  const int K = 2048;
  __shared__ ushort As[2][128*32];
  __shared__ ushort Bs[2][128*32];
  const int tid = threadIdx.x;
  const int wave = tid >> 6, lane = tid & 63;
  const int wm = wave >> 1, wn = wave & 1;
  const int quad = lane >> 4, l16 = lane & 15;
  const int swg = (l16 >> 1) & 3;
  // bijective XCD remap: 768 blocks = 8 XCDs * 96 contiguous tiles
  int id = blockIdx.y * 24 + blockIdx.x;
  id = (id & 7) * 96 + (id >> 3);
  const int bx = id % 24, by = id / 24;
  const int m0 = by * 128, n0 = bx * 128;

  f32x4 acc[4][4] = {};

  auto stage = [&](int buf, int k0) {
#pragma unroll
    for (int i = 0; i < 2; ++i) {
      int cbase = (i*4 + wave) * 64;
      int p = cbase + lane;
      int row = p >> 2, pcb = p & 3;
      int cl = pcb ^ ((row >> 1) & 3);
      g2l16(A  + (size_t)(m0 + row) * K + k0 + cl * 8, As[buf] + (size_t)cbase * 8);
      g2l16(Bw + (size_t)(n0 + row) * K + k0 + cl * 8, Bs[buf] + (size_t)cbase * 8);
    }
  };

  stage(0, 0);
  for (int k0 = 0; k0 < K; k0 += 32) {
    __syncthreads();
    int cur = (k0 >> 5) & 1;
    if (k0 + 32 < K) stage(cur ^ 1, k0 + 32);

    short8 af[4], bfr[4];
#pragma unroll
    for (int mi = 0; mi < 4; ++mi)
      af[mi] = *(const short8*)(As[cur] + (wm*64 + mi*16 + l16)*32 + ((quad ^ swg) * 8));
#pragma unroll
    for (int ni = 0; ni < 4; ++ni)
      bfr[ni] = *(const short8*)(Bs[cur] + (wn*64 + ni*16 + l16)*32 + ((quad ^ swg) * 8));
#pragma unroll
    for (int mi = 0; mi < 4; ++mi)
#pragma unroll
      for (int ni = 0; ni < 4; ++ni)
        acc[mi][ni] = MFMA16(af[mi], bfr[ni], acc[mi][ni]);
  }

  // ---- fused epilogue ----
  const int bb = m0 >> 11;                 // batch (uniform per block)
  const int tb = (m0 & 2047) + wm*64;      // token base for this wave

  if (bx < 20) {
    // q or k: rope pairs are (acc[.][ni], acc[.][ni+2]) = features (d, d+32)
    const bool isq = bx < 16;
    const float scale = isq ? QSCALE : 1.0f;
#pragma unroll
    for (int ni = 0; ni < 2; ++ni) {
      int n = n0 + wn*64 + ni*16 + l16;
      int d = ni*16 + l16;                 // = n&63, < 32
      float bias1, bias2;
      ushort* dst;
      if (isq) {
        bias1 = bq[n]; bias2 = bq[n + 32];
        dst = qr + ((size_t)(bb*32 + (n >> 6)) * 2048) * 64 + d;
      } else {
        bias1 = bk[n - 2048]; bias2 = bk[n - 2016];
        dst = kr + ((size_t)(bb*8 + ((n >> 6) - 32)) * 2048) * 64 + d;
      }
      float invf = exp2f((float)d * NFREQ);
#pragma unroll
      for (int mi = 0; mi < 4; ++mi) {
#pragma unroll
        for (int r = 0; r < 4; ++r) {
          int t = tb + mi*16 + quad*4 + r;
          float x1 = acc[mi][ni][r]   + bias1;
          float x2 = acc[mi][ni+2][r] + bias2;
          float f = (float)t * invf;
          float sn = __sinf(f), cs = __cosf(f);
          dst[(size_t)t*64]      = f2bf((x1*cs - x2*sn) * scale);
          dst[(size_t)t*64 + 32] = f2bf((x2*cs + x1*sn) * scale);
        }
      }
    }
  } else {
    // v: write transposed vt[b][hkv][d][t]; 4 consecutive t per b64 store
#pragma unroll
    for (int ni = 0; ni < 4; ++ni) {
      int n = n0 + wn*64 + ni*16 + l16;
      int d = ni*16 + l16;                 // = n&63
      float bias = bv[n - 2560];
      ushort* dst = vt + ((size_t)(bb*8 + ((n - 2560) >> 6)) * 64 + d) * 2048;
#pragma unroll
      for (int mi = 0; mi < 4; ++mi) {
        int t = tb + mi*16 + quad*4;
        uint2 pk;
        pk.x = (uint)f2bf(acc[mi][ni][0]+bias) | ((uint)f2bf(acc[mi][ni][1]+bias) << 16);
        pk.y = (uint)f2bf(acc[mi][ni][2]+bias) | ((uint)f2bf(acc[mi][ni][3]+bias) << 16);
        *(uint2*)(dst + t) = pk;
      }
    }
  }
}

// 128x128 GEMM (output projection), BK=32, dbuf, fp32 out + bias.
// XCD remap: 512 blocks = 8 * 64 contiguous tiles.
__global__ __launch_bounds__(256, 3)
void gemm128(const ushort* __restrict__ A, const ushort* __restrict__ Bw,
             const float* __restrict__ b0,
             float* __restrict__ Cout, int M, int N, int K) {
  __shared__ ushort As[2][128*32];
  __shared__ ushort Bs[2][128*32];
  const int tid = threadIdx.x;
  const int wave = tid >> 6, lane = tid & 63;
  const int wm = wave >> 1, wn = wave & 1;
  const int quad = lane >> 4, l16 = lane & 15;
  const int swg = (l16 >> 1) & 3;
  int id = blockIdx.y * 16 + blockIdx.x;
  id = (id & 7) * 64 + (id >> 3);
  const int m0 = (id / 16) * 128, n0 = (id % 16) * 128;

  f32x4 acc[4][4] = {};

  auto stage = [&](int buf, int k0) {
#pragma unroll
    for (int i = 0; i < 2; ++i) {
      int cbase = (i*4 + wave) * 64;
      int p = cbase + lane;
      int row = p >> 2, pcb = p & 3;
      int cl = pcb ^ ((row >> 1) & 3);
      g2l16(A  + (size_t)(m0 + row) * K + k0 + cl * 8, As[buf] + (size_t)cbase * 8);
      g2l16(Bw + (size_t)(n0 + row) * K + k0 + cl * 8, Bs[buf] + (size_t)cbase * 8);
    }
  };

  stage(0, 0);
  for (int k0 = 0; k0 < K; k0 += 32) {
    __syncthreads();
    int cur = (k0 >> 5) & 1;
    if (k0 + 32 < K) stage(cur ^ 1, k0 + 32);

    short8 af[4], bfr[4];
#pragma unroll
    for (int mi = 0; mi < 4; ++mi)
      af[mi] = *(const short8*)(As[cur] + (wm*64 + mi*16 + l16)*32 + ((quad ^ swg) * 8));
#pragma unroll
    for (int ni = 0; ni < 4; ++ni)
      bfr[ni] = *(const short8*)(Bs[cur] + (wn*64 + ni*16 + l16)*32 + ((quad ^ swg) * 8));
#pragma unroll
    for (int mi = 0; mi < 4; ++mi)
#pragma unroll
      for (int ni = 0; ni < 4; ++ni)
        acc[mi][ni] = MFMA16(af[mi], bfr[ni], acc[mi][ni]);
  }

#pragma unroll
  for (int ni = 0; ni < 4; ++ni) {
    int n = n0 + wn*64 + ni*16 + l16;
    float bias = b0[n];
#pragma unroll
    for (int mi = 0; mi < 4; ++mi) {
#pragma unroll
      for (int r = 0; r < 4; ++r) {
        int m = m0 + wm*64 + mi*16 + quad*4 + r;
        Cout[(size_t)m * N + n] = acc[mi][ni][r] + bias;
      }
    }
  }
}

// Flash attention, causal, GQA, shift-free exp2 softmax. 32x32x16 MFMA.
// R12: NO LDS, NO barriers. K/V fragments read directly from global
// (per-tile working set 16KB fits L1; 4-wave re-reads are L1 hits; KV
// arrays L2-resident via chunk remap: XCD k hosts heads 8k..8k+7 = 1MB).
// 4 waves x 32 q-rows = 128-row Q-tile; P in-register via pkbf +
// permlane32_swap (T12). 2-pass (qt,15-qt) for constant per-block work.
// 32x32 C-layout: col = lane&31, row = (reg&3) + 8*(reg>>2) + 4*(lane>>5).
__global__ __launch_bounds__(256, 2)
void attn(const ushort* __restrict__ Q, const ushort* __restrict__ Kb,
          const ushort* __restrict__ Vt, ushort* __restrict__ Y) {
  const int tid = threadIdx.x, wave = tid >> 6, lane = tid & 63;
  const int l32 = lane & 31, hh = lane >> 5;
  // bijective chunk remap: XCD k (= lin%8) gets work-ids [64k, 64k+64)
  // = 8 consecutive heads (2 KV pairs) of one batch.
  int lin = blockIdx.z * 256 + blockIdx.y * 8 + blockIdx.x;
  int wid = (lin & 7) * 64 + (lin >> 3);
  const int xq = wid & 7;
  const int h = (wid >> 3) & 31, b = wid >> 8;
  const int hk = h >> 2;
  const ushort* Qb = Q  + ((size_t)(b*32 + h)  * 2048) * 64;
  const ushort* Kg = Kb + ((size_t)(b*8 + hk) * 2048) * 64;
  const ushort* Vg = Vt + ((size_t)(b*8 + hk) * 64) * 2048;

  for (int pass = 0; pass < 2; ++pass) {
    const int qt = pass ? (15 - xq) : xq;
    const int q0 = qt * 128;
    const int qrow = q0 + wave*32 + l32;
    // Q B-frags: for kstep ks, lane holds col q=qrow, d = ks*16 + hh*8 + j
    short8 qf[4];
#pragma unroll
    for (int ks = 0; ks < 4; ++ks)
      qf[ks] = *(const short8*)(Qb + (size_t)qrow*64 + ks*16 + hh*8);

    f32x16 o[2] = {};     // O^T: db*32 + rowmap = d, col = q
    float lsum = 0.f;

    const int ktmax = qt*2 + 1;
    for (int kt = 0; kt <= ktmax; ++kt) {
      const bool band = (kt*64 + 63 > q0 + wave*32);   // tile reaches wave-min q

#pragma unroll
      for (int kb = 0; kb < 2; ++kb) {
        // S^T = K Q^T for this 32-key block, K=64 over 4 ksteps (direct global)
        f32x16 s = {};
        __builtin_amdgcn_s_setprio(1);
#pragma unroll
        for (int ks = 0; ks < 4; ++ks) {
          short8 kf = *(const short8*)(Kg + (size_t)(kt*64 + kb*32 + l32)*64 + ks*16 + hh*8);
          s = MFMA32(kf, qf[ks], s);
        }
        __builtin_amdgcn_s_setprio(0);

        // causal mask: gate on wave-MIN q; per-lane key>qrow check is exact
        if (band) {
#pragma unroll
          for (int r = 0; r < 16; ++r) {
            int key = kt*64 + kb*32 + (r & 3) + 8*(r >> 2) + 4*hh;
            if (key > qrow) s[r] = -INFINITY;
          }
        }

        // shift-free: p = exp2(s); exp2(-inf)=0 handles the mask
#pragma unroll
        for (int r = 0; r < 16; ++r) {
          s[r] = __builtin_amdgcn_exp2f(s[r]);
          lsum += s[r];
        }

        // P -> bf16 B-frags in-register, then PV for this 32-key block
        __builtin_amdgcn_s_setprio(1);
#pragma unroll
        for (int c = 0; c < 2; ++c) {
          int rb = c*8;
          uint a0 = pkbf(s[rb+0], s[rb+1]);
          uint b0 = pkbf(s[rb+4], s[rb+5]);
          uint a1 = pkbf(s[rb+2], s[rb+3]);
          uint b1 = pkbf(s[rb+6], s[rb+7]);
          uint2v r0 = __builtin_amdgcn_permlane32_swap(a0, b0, false, false);
          uint2v r1 = __builtin_amdgcn_permlane32_swap(a1, b1, false, false);
          union { uint u[4]; short8 s8; } pa;
          pa.u[0] = r0[0]; pa.u[1] = r1[0]; pa.u[2] = r0[1]; pa.u[3] = r1[1];
          // O^T += V^T P^T for this 16-key step (V direct from global V^T)
#pragma unroll
          for (int db = 0; db < 2; ++db) {
            short8 vf = *(const short8*)(Vg + (size_t)(db*32 + l32)*2048
                                            + kt*64 + (kb*4 + c*2 + hh)*8);
            o[db] = MFMA32(vf, pa.s8, o[db]);
          }
        }
        __builtin_amdgcn_s_setprio(0);
      }
    }

    // combine denominator across lane halves (lanes l and l^32 share q-col)
    union { float f; uint u; } lu; lu.f = lsum;
    uint2v lr = __builtin_amdgcn_permlane32_swap(lu.u, lu.u, false, false);
    union { uint u; float f; } la, lb; la.u = lr[0]; lb.u = lr[1];
    float inv = 1.0f / (la.f + lb.f);

    // write Y[b][q][h*64 + d]: per db, 4 runs of 4 consecutive d
#pragma unroll
    for (int db = 0; db < 2; ++db) {
#pragma unroll
      for (int g = 0; g < 4; ++g) {
        int d = db*32 + 8*g + 4*hh;
        size_t base = ((size_t)(b*2048 + qrow)) * 2048 + h*64 + d;
        uint2 pk;
        pk.x = pkbf(o[db][4*g+0]*inv, o[db][4*g+1]*inv);
        pk.y = pkbf(o[db][4*g+2]*inv, o[db][4*g+3]*inv);
        *(uint2*)((ushort*)Y + base) = pk;
      }
    }
  }
}

extern "C" void kernel_launch(void* const* d_in, const int* in_sizes, int n_in,
                              void* d_out, int out_size, void* d_ws, size_t ws_size,
                              hipStream_t stream) {
  (void)in_sizes; (void)n_in; (void)out_size; (void)ws_size;
  const float* x  = (const float*)d_in[0];
  const float* Wq = (const float*)d_in[1];
  const float* bq = (const float*)d_in[2];
  const float* Wk = (const float*)d_in[3];
  const float* bk = (const float*)d_in[4];
  const float* Wv = (const float*)d_in[5];
  const float* bv = (const float*)d_in[6];
  const float* Wo = (const float*)d_in[7];
  const float* bo = (const float*)d_in[8];
  float* out = (float*)d_out;

  ushort* ws    = (ushort*)d_ws;
  ushort* x_bf  = ws;                        // 8388608
  ushort* wqkv  = x_bf + 8388608;            // 6291456  [3072][2048]
  ushort* wo_bf = wqkv + 6291456;            // 4194304
  ushort* qr    = wo_bf + 4194304;           // 8388608  [2][32][2048][64]
  ushort* kr    = qr + 8388608;              // 2097152  [2][8][2048][64]
  ushort* vt    = kr + 2097152;              // 2097152  [2][8][64][2048]
  ushort* Y     = x_bf;                      // x_bf dead after gemm_qkv

  cvt_all<<<18432, 256, 0, stream>>>(x, Wq, Wk, Wv, Wo, x_bf, wqkv, wo_bf);
  gemm_qkv<<<dim3(24, 32), 256, 0, stream>>>(x_bf, wqkv, bq, bk, bv, qr, kr, vt);
  attn<<<dim3(8, 32, 2), 256, 0, stream>>>(qr, kr, vt, Y);
  gemm128<<<dim3(16, 32), 256, 0, stream>>>(Y, wo_bf, bo, out, 4096, 2048, 2048);
}

// Round 8
// 298.505 us; speedup vs baseline: 1.2199x; 1.2199x over previous
//
#include <hip/hip_runtime.h>
#include <hip/hip_bf16.h>
#include <math.h>

// Attention block: y = out_proj(causal_softmax(rope(q)·rope(k)^T)·v)
// B=2 T=2048 C=2048 Hq=32 Hkv=8 D=64. bf16 MFMA, fp32 accumulate.
// R13: attn back to LDS-staged 32x32 (R12's direct-global was latency-bound:
// 138µs, MfmaUtil 10%) + kt-PARITY SPLIT for 2x occupancy. Mechanism: attn
// is dependency-latency bound (MFMA floor 3.4µs, VALU ~10µs/SIMD, yet 61µs
// measured) at 2 waves/SIMD. Shift-free softmax has no running max -> O,l
// are order-free sums -> kt loop is splittable. 8 waves/block: waves 0-3
// take even kt, 4-7 odd kt of the same (qt,15-qt) pair; each parity gets
// exactly qt+1 tiles (lockstep barriers safe, block work constant). Private
// per-parity K/V dbuf (64KB; 2 blocks/CU = 128KB). End-of-pass combine via
// LDS (bank-XOR chunk layout). 4 waves/SIMD hides the serial tile chain.
// GEMMs unchanged (XCD-swizzled 128x128; 2.58 TF/CU wall stands).

typedef __attribute__((ext_vector_type(8))) short short8;
typedef __attribute__((ext_vector_type(4))) float f32x4;
typedef __attribute__((ext_vector_type(16))) float f32x16;
typedef __attribute__((ext_vector_type(2))) unsigned int uint2v;

#define MFMA16(a,b,c) __builtin_amdgcn_mfma_f32_16x16x32_bf16((a),(b),(c),0,0,0)
#define MFMA32(a,b,c) __builtin_amdgcn_mfma_f32_32x32x16_bf16((a),(b),(c),0,0,0)
#define QSCALE 0.18033688011112043f   // (1/sqrt(64))*log2(e): exp2-domain softmax
#define NFREQ  (-13.28771237954945f / 32.0f)  // -log2(10000)/32

__device__ __forceinline__ ushort f2bf(float f) {
  union { float f; unsigned u; } x; x.f = f;
  unsigned r = x.u + 0x7fffu + ((x.u >> 16) & 1u);   // RNE
  return (ushort)(r >> 16);
}
// round-half-up packed bf16 pair (5 int ops)
__device__ __forceinline__ uint pkbf(float a, float b) {
  union { float f; unsigned u; } x, y; x.f = a; y.f = b;
  return ((x.u + 0x8000u) >> 16) | ((y.u + 0x8000u) & 0xffff0000u);
}

__device__ __forceinline__ void g2l16(const void* g, void* l) {
  __builtin_amdgcn_global_load_lds(
      (__attribute__((address_space(1))) void*)g,
      (__attribute__((address_space(3))) void*)l, 16, 0, 0);
}

// one kernel for all fp32->bf16 conversions
__global__ void cvt_all(const float* __restrict__ x,  const float* __restrict__ wq,
                        const float* __restrict__ wk, const float* __restrict__ wv,
                        const float* __restrict__ wo,
                        ushort* __restrict__ x_bf, ushort* __restrict__ wqkv,
                        ushort* __restrict__ wo_bf) {
  int i = blockIdx.x * 256 + threadIdx.x;
  const float4* src; ushort* dst; int off;
  if (i < 2097152)      { src = (const float4*)x;  dst = x_bf;             off = i; }
  else if (i < 3145728) { src = (const float4*)wq; dst = wqkv;             off = i - 2097152; }
  else if (i < 3407872) { src = (const float4*)wk; dst = wqkv + 4194304;   off = i - 3145728; }
  else if (i < 3670016) { src = (const float4*)wv; dst = wqkv + 5242880;   off = i - 3407872; }
  else                  { src = (const float4*)wo; dst = wo_bf;            off = i - 3670016; }
  float4 v = src[off];
  ushort4 o;
  o.x = f2bf(v.x); o.y = f2bf(v.y); o.z = f2bf(v.z); o.w = f2bf(v.w);
  ((ushort4*)dst)[off] = o;
}

// QKV GEMM with fused RoPE/scatter epilogue. M=4096, N=3072, K=2048,
// grid (24,32) remapped so each XCD computes 96 contiguous tiles (4 y-rows):
// A-panels stay L2-local per XCD. Col-segment (swizzled bx): bx<16 -> q
// (rope+QSCALE -> qr), 16..19 -> k (rope -> kr), 20..23 -> v (-> vt).
__global__ __launch_bounds__(256, 3)
void gemm_qkv(const ushort* __restrict__ A, const ushort* __restrict__ Bw,
              const float* __restrict__ bq, const float* __restrict__ bk,
              const float* __restrict__ bv,
              ushort* __restrict__ qr, ushort* __restrict__ kr,
              ushort* __restrict__ vt) {
  const int K = 2048;
  __shared__ ushort As[2][128*32];
  __shared__ ushort Bs[2][128*32];
  const int tid = threadIdx.x;
  const int wave = tid >> 6, lane = tid & 63;
  const int wm = wave >> 1, wn = wave & 1;
  const int quad = lane >> 4, l16 = lane & 15;
  const int swg = (l16 >> 1) & 3;
  // bijective XCD remap: 768 blocks = 8 XCDs * 96 contiguous tiles
  int id = blockIdx.y * 24 + blockIdx.x;
  id = (id & 7) * 96 + (id >> 3);
  const int bx = id % 24, by = id / 24;
  const int m0 = by * 128, n0 = bx * 128;

  f32x4 acc[4][4] = {};

  auto stage = [&](int buf, int k0) {
#pragma unroll
    for (int i = 0; i < 2; ++i) {
      int cbase = (i*4 + wave) * 64;
      int p = cbase + lane;
      int row = p >> 2, pcb = p & 3;
      int cl = pcb ^ ((row >> 1) & 3);
      g2l16(A  + (size_t)(m0 + row) * K + k0 + cl * 8, As[buf] + (size_t)cbase * 8);
      g2l16(Bw + (size_t)(n0 + row) * K + k0 + cl * 8, Bs[buf] + (size_t)cbase * 8);
    }
  };

  stage(0, 0);
  for (int k0 = 0; k0 < K; k0 += 32) {
    __syncthreads();
    int cur = (k0 >> 5) & 1;
    if (k0 + 32 < K) stage(cur ^ 1, k0 + 32);

    short8 af[4], bfr[4];
#pragma unroll
    for (int mi = 0; mi < 4; ++mi)
      af[mi] = *(const short8*)(As[cur] + (wm*64 + mi*16 + l16)*32 + ((quad ^ swg) * 8));
#pragma unroll
    for (int ni = 0; ni < 4; ++ni)
      bfr[ni] = *(const short8*)(Bs[cur] + (wn*64 + ni*16 + l16)*32 + ((quad ^ swg) * 8));
#pragma unroll
    for (int mi = 0; mi < 4; ++mi)
#pragma unroll
      for (int ni = 0; ni < 4; ++ni)
        acc[mi][ni] = MFMA16(af[mi], bfr[ni], acc[mi][ni]);
  }

  // ---- fused epilogue ----
  const int bb = m0 >> 11;                 // batch (uniform per block)
  const int tb = (m0 & 2047) + wm*64;      // token base for this wave

  if (bx < 20) {
    // q or k: rope pairs are (acc[.][ni], acc[.][ni+2]) = features (d, d+32)
    const bool isq = bx < 16;
    const float scale = isq ? QSCALE : 1.0f;
#pragma unroll
    for (int ni = 0; ni < 2; ++ni) {
      int n = n0 + wn*64 + ni*16 + l16;
      int d = ni*16 + l16;                 // = n&63, < 32
      float bias1, bias2;
      ushort* dst;
      if (isq) {
        bias1 = bq[n]; bias2 = bq[n + 32];
        dst = qr + ((size_t)(bb*32 + (n >> 6)) * 2048) * 64 + d;
      } else {
        bias1 = bk[n - 2048]; bias2 = bk[n - 2016];
        dst = kr + ((size_t)(bb*8 + ((n >> 6) - 32)) * 2048) * 64 + d;
      }
      float invf = exp2f((float)d * NFREQ);
#pragma unroll
      for (int mi = 0; mi < 4; ++mi) {
#pragma unroll
        for (int r = 0; r < 4; ++r) {
          int t = tb + mi*16 + quad*4 + r;
          float x1 = acc[mi][ni][r]   + bias1;
          float x2 = acc[mi][ni+2][r] + bias2;
          float f = (float)t * invf;
          float sn = __sinf(f), cs = __cosf(f);
          dst[(size_t)t*64]      = f2bf((x1*cs - x2*sn) * scale);
          dst[(size_t)t*64 + 32] = f2bf((x2*cs + x1*sn) * scale);
        }
      }
    }
  } else {
    // v: write transposed vt[b][hkv][d][t]; 4 consecutive t per b64 store
#pragma unroll
    for (int ni = 0; ni < 4; ++ni) {
      int n = n0 + wn*64 + ni*16 + l16;
      int d = ni*16 + l16;                 // = n&63
      float bias = bv[n - 2560];
      ushort* dst = vt + ((size_t)(bb*8 + ((n - 2560) >> 6)) * 64 + d) * 2048;
#pragma unroll
      for (int mi = 0; mi < 4; ++mi) {
        int t = tb + mi*16 + quad*4;
        uint2 pk;
        pk.x = (uint)f2bf(acc[mi][ni][0]+bias) | ((uint)f2bf(acc[mi][ni][1]+bias) << 16);
        pk.y = (uint)f2bf(acc[mi][ni][2]+bias) | ((uint)f2bf(acc[mi][ni][3]+bias) << 16);
        *(uint2*)(dst + t) = pk;
      }
    }
  }
}

// 128x128 GEMM (output projection), BK=32, dbuf, fp32 out + bias.
// XCD remap: 512 blocks = 8 * 64 contiguous tiles.
__global__ __launch_bounds__(256, 3)
void gemm128(const ushort* __restrict__ A, const ushort* __restrict__ Bw,
             const float* __restrict__ b0,
             float* __restrict__ Cout, int M, int N, int K) {
  __shared__ ushort As[2][128*32];
  __shared__ ushort Bs[2][128*32];
  const int tid = threadIdx.x;
  const int wave = tid >> 6, lane = tid & 63;
  const int wm = wave >> 1, wn = wave & 1;
  const int quad = lane >> 4, l16 = lane & 15;
  const int swg = (l16 >> 1) & 3;
  int id = blockIdx.y * 16 + blockIdx.x;
  id = (id & 7) * 64 + (id >> 3);
  const int m0 = (id / 16) * 128, n0 = (id % 16) * 128;

  f32x4 acc[4][4] = {};

  auto stage = [&](int buf, int k0) {
#pragma unroll
    for (int i = 0; i < 2; ++i) {
      int cbase = (i*4 + wave) * 64;
      int p = cbase + lane;
      int row = p >> 2, pcb = p & 3;
      int cl = pcb ^ ((row >> 1) & 3);
      g2l16(A  + (size_t)(m0 + row) * K + k0 + cl * 8, As[buf] + (size_t)cbase * 8);
      g2l16(Bw + (size_t)(n0 + row) * K + k0 + cl * 8, Bs[buf] + (size_t)cbase * 8);
    }
  };

  stage(0, 0);
  for (int k0 = 0; k0 < K; k0 += 32) {
    __syncthreads();
    int cur = (k0 >> 5) & 1;
    if (k0 + 32 < K) stage(cur ^ 1, k0 + 32);

    short8 af[4], bfr[4];
#pragma unroll
    for (int mi = 0; mi < 4; ++mi)
      af[mi] = *(const short8*)(As[cur] + (wm*64 + mi*16 + l16)*32 + ((quad ^ swg) * 8));
#pragma unroll
    for (int ni = 0; ni < 4; ++ni)
      bfr[ni] = *(const short8*)(Bs[cur] + (wn*64 + ni*16 + l16)*32 + ((quad ^ swg) * 8));
#pragma unroll
    for (int mi = 0; mi < 4; ++mi)
#pragma unroll
      for (int ni = 0; ni < 4; ++ni)
        acc[mi][ni] = MFMA16(af[mi], bfr[ni], acc[mi][ni]);
  }

#pragma unroll
  for (int ni = 0; ni < 4; ++ni) {
    int n = n0 + wn*64 + ni*16 + l16;
    float bias = b0[n];
#pragma unroll
    for (int mi = 0; mi < 4; ++mi) {
#pragma unroll
      for (int r = 0; r < 4; ++r) {
        int m = m0 + wm*64 + mi*16 + quad*4 + r;
        Cout[(size_t)m * N + n] = acc[mi][ni][r] + bias;
      }
    }
  }
}

// Flash attention, causal, GQA, shift-free exp2 softmax. 32x32x16 MFMA.
// R13: 8 waves/block; kt-parity split (waves 0-3 even kt, 4-7 odd kt of the
// SAME q-tile). Order-free sums (no running max) make the split exact; each
// parity runs qt+1 tiles -> lockstep barriers, constant block work, 2-pass
// (qt,15-qt) balance kept. Private per-parity K/V double buffers (64KB).
// End-of-pass combine via LDS with bank-XOR chunk layout. 4 waves/SIMD.
// 32x32 C-layout: col = lane&31, row = (reg&3) + 8*(reg>>2) + 4*(lane>>5).
__global__ __launch_bounds__(512, 4)
void attn(const ushort* __restrict__ Q, const ushort* __restrict__ Kb,
          const ushort* __restrict__ Vt, ushort* __restrict__ Y) {
  __shared__ ushort Ks[2][2][64*64];   // [parity][buf]
  __shared__ ushort Vs[2][2][64*64];
  const int tid = threadIdx.x, wave = tid >> 6, lane = tid & 63;
  const int wq = wave & 3;             // q-row quad (32 rows each)
  const int par = wave >> 2;           // kt parity
  const int l32 = lane & 31, hh = lane >> 5;
  const int h = blockIdx.y, b = blockIdx.z;
  const int hk = h >> 2;
  const ushort* Qb = Q  + ((size_t)(b*32 + h)  * 2048) * 64;
  const ushort* Kg = Kb + ((size_t)(b*8 + hk) * 2048) * 64;
  const ushort* Vg = Vt + ((size_t)(b*8 + hk) * 64) * 2048;

  // stage one 64x64 K tile + one 64x64 V tile into this parity's buffer;
  // chunk-XOR swizzle on the global source (LDS dest linear per g2l16 rules)
  auto stage = [&](int buf, int kt) {
    int qtid = wq*64 + lane;           // 0..255 within the parity quad
#pragma unroll
    for (int i = 0; i < 2; ++i) {
      int p = i*256 + qtid;
      int row = p >> 3, pcb = p & 7;
      int cl = pcb ^ (row & 7);
      g2l16(Kg + (size_t)(kt*64 + row)*64 + cl*8, Ks[par][buf] + (size_t)p*8);
      g2l16(Vg + (size_t)row*2048 + kt*64 + cl*8, Vs[par][buf] + (size_t)p*8);
    }
  };

  for (int pass = 0; pass < 2; ++pass) {
    const int qt = pass ? (15 - blockIdx.x) : blockIdx.x;   // pair (qt, 15-qt)
    const int q0 = qt * 128;
    const int qrow = q0 + wq*32 + l32;
    // Q B-frags: for kstep ks, lane holds col q=qrow, d = ks*16 + hh*8 + j
    short8 qf[4];
#pragma unroll
    for (int ks = 0; ks < 4; ++ks)
      qf[ks] = *(const short8*)(Qb + (size_t)qrow*64 + ks*16 + hh*8);

    f32x16 o[2] = {};     // O^T partial (this parity): rows d, col q
    float lsum = 0.f;

    __syncthreads();            // LDS handoff (prev pass exchange reads done)
    const int nt = qt + 1;      // tiles for this parity: kt = par, par+2, ...
    stage(0, par);

    for (int it = 0; it < nt; ++it) {
      const int kt = par + it*2;
      __syncthreads();          // drain staging issued one step ago
      int cur = it & 1;
      if (it + 1 < nt) stage(cur ^ 1, kt + 2);

      const ushort* Kl = Ks[par][cur];
      const ushort* Vl = Vs[par][cur];
      const bool band = (kt*64 + 63 > q0 + wq*32);   // tile reaches wave-min q

#pragma unroll
      for (int kb = 0; kb < 2; ++kb) {
        // S^T = K Q^T for this 32-key block, K=64 over 4 ksteps
        f32x16 s = {};
        __builtin_amdgcn_s_setprio(1);
#pragma unroll
        for (int ks = 0; ks < 4; ++ks) {
          int row = kb*32 + l32;
          short8 kf = *(const short8*)(Kl + row*64 + (((ks*2 + hh) ^ (row & 7)) * 8));
          s = MFMA32(kf, qf[ks], s);
        }
        __builtin_amdgcn_s_setprio(0);

        // causal mask: gate on wave-MIN q; per-lane key>qrow check is exact
        if (band) {
#pragma unroll
          for (int r = 0; r < 16; ++r) {
            int key = kt*64 + kb*32 + (r & 3) + 8*(r >> 2) + 4*hh;
            if (key > qrow) s[r] = -INFINITY;
          }
        }

        // shift-free: p = exp2(s); exp2(-inf)=0 handles the mask
#pragma unroll
        for (int r = 0; r < 16; ++r) {
          s[r] = __builtin_amdgcn_exp2f(s[r]);
          lsum += s[r];
        }

        // P -> bf16 B-frags in-register, then PV for this 32-key block
        __builtin_amdgcn_s_setprio(1);
#pragma unroll
        for (int c = 0; c < 2; ++c) {
          int rb = c*8;
          uint a0 = pkbf(s[rb+0], s[rb+1]);
          uint b0 = pkbf(s[rb+4], s[rb+5]);
          uint a1 = pkbf(s[rb+2], s[rb+3]);
          uint b1 = pkbf(s[rb+6], s[rb+7]);
          uint2v r0 = __builtin_amdgcn_permlane32_swap(a0, b0, false, false);
          uint2v r1 = __builtin_amdgcn_permlane32_swap(a1, b1, false, false);
          union { uint u[4]; short8 s8; } pa;
          pa.u[0] = r0[0]; pa.u[1] = r1[0]; pa.u[2] = r0[1]; pa.u[3] = r1[1];
#pragma unroll
          for (int db = 0; db < 2; ++db) {
            int row = db*32 + l32;
            short8 vf = *(const short8*)(Vl + row*64 +
                          (((kb*4 + c*2 + hh) ^ (row & 7)) * 8));
            o[db] = MFMA32(vf, pa.s8, o[db]);
          }
        }
        __builtin_amdgcn_s_setprio(0);
      }
    }

    // ---- cross-parity combine (Ks reused as 32KB fp32 exchange) ----
    __syncthreads();                       // all K/V LDS reads done
    float* ex  = (float*)&Ks[0][0][0];     // 8192 floats
    float* exl = (float*)&Vs[0][0][0];     // 256 floats
    const int basei = (wq*64 + lane) * 32;
    if (par == 1) {
#pragma unroll
      for (int db = 0; db < 2; ++db)
#pragma unroll
        for (int j = 0; j < 4; ++j) {
          int cc = db*4 + j;               // bank-XOR chunk layout: 2/bank
          f32x4 v = { o[db][4*j+0], o[db][4*j+1], o[db][4*j+2], o[db][4*j+3] };
          *(f32x4*)&ex[basei + ((cc ^ (lane & 7)) << 2)] = v;
        }
      exl[wq*64 + lane] = lsum;
    }
    __syncthreads();
    if (par == 0) {
#pragma unroll
      for (int db = 0; db < 2; ++db)
#pragma unroll
        for (int j = 0; j < 4; ++j) {
          int cc = db*4 + j;
          f32x4 v = *(const f32x4*)&ex[basei + ((cc ^ (lane & 7)) << 2)];
          o[db][4*j+0] += v[0]; o[db][4*j+1] += v[1];
          o[db][4*j+2] += v[2]; o[db][4*j+3] += v[3];
        }
      lsum += exl[wq*64 + lane];

      // combine denominator across lane halves (lanes l, l^32 share q-col)
      union { float f; uint u; } lu; lu.f = lsum;
      uint2v lr = __builtin_amdgcn_permlane32_swap(lu.u, lu.u, false, false);
      union { uint u; float f; } la, lb2; la.u = lr[0]; lb2.u = lr[1];
      float inv = 1.0f / (la.f + lb2.f);

      // write Y[b][q][h*64 + d]: per db, 4 runs of 4 consecutive d
#pragma unroll
      for (int db = 0; db < 2; ++db)
#pragma unroll
        for (int g = 0; g < 4; ++g) {
          int d = db*32 + 8*g + 4*hh;
          size_t base = ((size_t)(b*2048 + qrow)) * 2048 + h*64 + d;
          uint2 pk;
          pk.x = pkbf(o[db][4*g+0]*inv, o[db][4*g+1]*inv);
          pk.y = pkbf(o[db][4*g+2]*inv, o[db][4*g+3]*inv);
          *(uint2*)((ushort*)Y + base) = pk;
        }
    }
  }
}

extern "C" void kernel_launch(void* const* d_in, const int* in_sizes, int n_in,
                              void* d_out, int out_size, void* d_ws, size_t ws_size,
                              hipStream_t stream) {
  (void)in_sizes; (void)n_in; (void)out_size; (void)ws_size;
  const float* x  = (const float*)d_in[0];
  const float* Wq = (const float*)d_in[1];
  const float* bq = (const float*)d_in[2];
  const float* Wk = (const float*)d_in[3];
  const float* bk = (const float*)d_in[4];
  const float* Wv = (const float*)d_in[5];
  const float* bv = (const float*)d_in[6];
  const float* Wo = (const float*)d_in[7];
  const float* bo = (const float*)d_in[8];
  float* out = (float*)d_out;

  ushort* ws    = (ushort*)d_ws;
  ushort* x_bf  = ws;                        // 8388608
  ushort* wqkv  = x_bf + 8388608;            // 6291456  [3072][2048]
  ushort* wo_bf = wqkv + 6291456;            // 4194304
  ushort* qr    = wo_bf + 4194304;           // 8388608  [2][32][2048][64]
  ushort* kr    = qr + 8388608;              // 2097152  [2][8][2048][64]
  ushort* vt    = kr + 2097152;              // 2097152  [2][8][64][2048]
  ushort* Y     = x_bf;                      // x_bf dead after gemm_qkv

  cvt_all<<<18432, 256, 0, stream>>>(x, Wq, Wk, Wv, Wo, x_bf, wqkv, wo_bf);
  gemm_qkv<<<dim3(24, 32), 256, 0, stream>>>(x_bf, wqkv, bq, bk, bv, qr, kr, vt);
  attn<<<dim3(8, 32, 2), 512, 0, stream>>>(qr, kr, vt, Y);
  gemm128<<<dim3(16, 32), 256, 0, stream>>>(Y, wo_bf, bo, out, 4096, 2048, 2048);
}

// Round 9
// 283.670 us; speedup vs baseline: 1.2837x; 1.0523x over previous
//
#include <hip/hip_runtime.h>
#include <hip/hip_bf16.h>
#include <math.h>

// Attention block: y = out_proj(causal_softmax(rope(q)·rope(k)^T)·v)
// B=2 T=2048 C=2048 Hq=32 Hkv=8 D=64. bf16 MFMA, fp32 accumulate.
// R14: attn reverted to the proven R5 structure (2-pass qt-pairing, 4 waves,
// LDS-staged K/V, 32x32 MFMA, in-register P) with KVBLK 64->128:
//  * barriers per pass: 2qt+3 -> qt+2 (each barrier = full staging drain)
//  * prefetch lead doubled (stage t+1 issued a 128-key compute ahead)
//  * kv-tile == q-tile size -> diagonal tile is exactly kt==qt; wave w skips
//    fully-masked 32-key blocks kb>w (saves ~37% of diagonal MFMA)
//  * LDS 64KB -- free, since the 512-block grid caps us at 2 blocks/CU anyway
// R8's kt-parity split regressed (8-wave lockstep barriers + combine ate the
// occupancy gain) -- reverted. GEMMs unchanged (XCD-swizzled 128x128).

typedef __attribute__((ext_vector_type(8))) short short8;
typedef __attribute__((ext_vector_type(4))) float f32x4;
typedef __attribute__((ext_vector_type(16))) float f32x16;
typedef __attribute__((ext_vector_type(2))) unsigned int uint2v;

#define MFMA16(a,b,c) __builtin_amdgcn_mfma_f32_16x16x32_bf16((a),(b),(c),0,0,0)
#define MFMA32(a,b,c) __builtin_amdgcn_mfma_f32_32x32x16_bf16((a),(b),(c),0,0,0)
#define QSCALE 0.18033688011112043f   // (1/sqrt(64))*log2(e): exp2-domain softmax
#define NFREQ  (-13.28771237954945f / 32.0f)  // -log2(10000)/32

__device__ __forceinline__ ushort f2bf(float f) {
  union { float f; unsigned u; } x; x.f = f;
  unsigned r = x.u + 0x7fffu + ((x.u >> 16) & 1u);   // RNE
  return (ushort)(r >> 16);
}
// round-half-up packed bf16 pair (5 int ops)
__device__ __forceinline__ uint pkbf(float a, float b) {
  union { float f; unsigned u; } x, y; x.f = a; y.f = b;
  return ((x.u + 0x8000u) >> 16) | ((y.u + 0x8000u) & 0xffff0000u);
}

__device__ __forceinline__ void g2l16(const void* g, void* l) {
  __builtin_amdgcn_global_load_lds(
      (__attribute__((address_space(1))) void*)g,
      (__attribute__((address_space(3))) void*)l, 16, 0, 0);
}

// one kernel for all fp32->bf16 conversions
__global__ void cvt_all(const float* __restrict__ x,  const float* __restrict__ wq,
                        const float* __restrict__ wk, const float* __restrict__ wv,
                        const float* __restrict__ wo,
                        ushort* __restrict__ x_bf, ushort* __restrict__ wqkv,
                        ushort* __restrict__ wo_bf) {
  int i = blockIdx.x * 256 + threadIdx.x;
  const float4* src; ushort* dst; int off;
  if (i < 2097152)      { src = (const float4*)x;  dst = x_bf;             off = i; }
  else if (i < 3145728) { src = (const float4*)wq; dst = wqkv;             off = i - 2097152; }
  else if (i < 3407872) { src = (const float4*)wk; dst = wqkv + 4194304;   off = i - 3145728; }
  else if (i < 3670016) { src = (const float4*)wv; dst = wqkv + 5242880;   off = i - 3407872; }
  else                  { src = (const float4*)wo; dst = wo_bf;            off = i - 3670016; }
  float4 v = src[off];
  ushort4 o;
  o.x = f2bf(v.x); o.y = f2bf(v.y); o.z = f2bf(v.z); o.w = f2bf(v.w);
  ((ushort4*)dst)[off] = o;
}

// QKV GEMM with fused RoPE/scatter epilogue. M=4096, N=3072, K=2048,
// grid (24,32) remapped so each XCD computes 96 contiguous tiles (4 y-rows):
// A-panels stay L2-local per XCD. Col-segment (swizzled bx): bx<16 -> q
// (rope+QSCALE -> qr), 16..19 -> k (rope -> kr), 20..23 -> v (-> vt).
__global__ __launch_bounds__(256, 3)
void gemm_qkv(const ushort* __restrict__ A, const ushort* __restrict__ Bw,
              const float* __restrict__ bq, const float* __restrict__ bk,
              const float* __restrict__ bv,
              ushort* __restrict__ qr, ushort* __restrict__ kr,
              ushort* __restrict__ vt) {
  const int K = 2048;
  __shared__ ushort As[2][128*32];
  __shared__ ushort Bs[2][128*32];
  const int tid = threadIdx.x;
  const int wave = tid >> 6, lane = tid & 63;
  const int wm = wave >> 1, wn = wave & 1;
  const int quad = lane >> 4, l16 = lane & 15;
  const int swg = (l16 >> 1) & 3;
  // bijective XCD remap: 768 blocks = 8 XCDs * 96 contiguous tiles
  int id = blockIdx.y * 24 + blockIdx.x;
  id = (id & 7) * 96 + (id >> 3);
  const int bx = id % 24, by = id / 24;
  const int m0 = by * 128, n0 = bx * 128;

  f32x4 acc[4][4] = {};

  auto stage = [&](int buf, int k0) {
#pragma unroll
    for (int i = 0; i < 2; ++i) {
      int cbase = (i*4 + wave) * 64;
      int p = cbase + lane;
      int row = p >> 2, pcb = p & 3;
      int cl = pcb ^ ((row >> 1) & 3);
      g2l16(A  + (size_t)(m0 + row) * K + k0 + cl * 8, As[buf] + (size_t)cbase * 8);
      g2l16(Bw + (size_t)(n0 + row) * K + k0 + cl * 8, Bs[buf] + (size_t)cbase * 8);
    }
  };

  stage(0, 0);
  for (int k0 = 0; k0 < K; k0 += 32) {
    __syncthreads();
    int cur = (k0 >> 5) & 1;
    if (k0 + 32 < K) stage(cur ^ 1, k0 + 32);

    short8 af[4], bfr[4];
#pragma unroll
    for (int mi = 0; mi < 4; ++mi)
      af[mi] = *(const short8*)(As[cur] + (wm*64 + mi*16 + l16)*32 + ((quad ^ swg) * 8));
#pragma unroll
    for (int ni = 0; ni < 4; ++ni)
      bfr[ni] = *(const short8*)(Bs[cur] + (wn*64 + ni*16 + l16)*32 + ((quad ^ swg) * 8));
#pragma unroll
    for (int mi = 0; mi < 4; ++mi)
#pragma unroll
      for (int ni = 0; ni < 4; ++ni)
        acc[mi][ni] = MFMA16(af[mi], bfr[ni], acc[mi][ni]);
  }

  // ---- fused epilogue ----
  const int bb = m0 >> 11;                 // batch (uniform per block)
  const int tb = (m0 & 2047) + wm*64;      // token base for this wave

  if (bx < 20) {
    // q or k: rope pairs are (acc[.][ni], acc[.][ni+2]) = features (d, d+32)
    const bool isq = bx < 16;
    const float scale = isq ? QSCALE : 1.0f;
#pragma unroll
    for (int ni = 0; ni < 2; ++ni) {
      int n = n0 + wn*64 + ni*16 + l16;
      int d = ni*16 + l16;                 // = n&63, < 32
      float bias1, bias2;
      ushort* dst;
      if (isq) {
        bias1 = bq[n]; bias2 = bq[n + 32];
        dst = qr + ((size_t)(bb*32 + (n >> 6)) * 2048) * 64 + d;
      } else {
        bias1 = bk[n - 2048]; bias2 = bk[n - 2016];
        dst = kr + ((size_t)(bb*8 + ((n >> 6) - 32)) * 2048) * 64 + d;
      }
      float invf = exp2f((float)d * NFREQ);
#pragma unroll
      for (int mi = 0; mi < 4; ++mi) {
#pragma unroll
        for (int r = 0; r < 4; ++r) {
          int t = tb + mi*16 + quad*4 + r;
          float x1 = acc[mi][ni][r]   + bias1;
          float x2 = acc[mi][ni+2][r] + bias2;
          float f = (float)t * invf;
          float sn = __sinf(f), cs = __cosf(f);
          dst[(size_t)t*64]      = f2bf((x1*cs - x2*sn) * scale);
          dst[(size_t)t*64 + 32] = f2bf((x2*cs + x1*sn) * scale);
        }
      }
    }
  } else {
    // v: write transposed vt[b][hkv][d][t]; 4 consecutive t per b64 store
#pragma unroll
    for (int ni = 0; ni < 4; ++ni) {
      int n = n0 + wn*64 + ni*16 + l16;
      int d = ni*16 + l16;                 // = n&63
      float bias = bv[n - 2560];
      ushort* dst = vt + ((size_t)(bb*8 + ((n - 2560) >> 6)) * 64 + d) * 2048;
#pragma unroll
      for (int mi = 0; mi < 4; ++mi) {
        int t = tb + mi*16 + quad*4;
        uint2 pk;
        pk.x = (uint)f2bf(acc[mi][ni][0]+bias) | ((uint)f2bf(acc[mi][ni][1]+bias) << 16);
        pk.y = (uint)f2bf(acc[mi][ni][2]+bias) | ((uint)f2bf(acc[mi][ni][3]+bias) << 16);
        *(uint2*)(dst + t) = pk;
      }
    }
  }
}

// 128x128 GEMM (output projection), BK=32, dbuf, fp32 out + bias.
// XCD remap: 512 blocks = 8 * 64 contiguous tiles.
__global__ __launch_bounds__(256, 3)
void gemm128(const ushort* __restrict__ A, const ushort* __restrict__ Bw,
             const float* __restrict__ b0,
             float* __restrict__ Cout, int M, int N, int K) {
  __shared__ ushort As[2][128*32];
  __shared__ ushort Bs[2][128*32];
  const int tid = threadIdx.x;
  const int wave = tid >> 6, lane = tid & 63;
  const int wm = wave >> 1, wn = wave & 1;
  const int quad = lane >> 4, l16 = lane & 15;
  const int swg = (l16 >> 1) & 3;
  int id = blockIdx.y * 16 + blockIdx.x;
  id = (id & 7) * 64 + (id >> 3);
  const int m0 = (id / 16) * 128, n0 = (id % 16) * 128;

  f32x4 acc[4][4] = {};

  auto stage = [&](int buf, int k0) {
#pragma unroll
    for (int i = 0; i < 2; ++i) {
      int cbase = (i*4 + wave) * 64;
      int p = cbase + lane;
      int row = p >> 2, pcb = p & 3;
      int cl = pcb ^ ((row >> 1) & 3);
      g2l16(A  + (size_t)(m0 + row) * K + k0 + cl * 8, As[buf] + (size_t)cbase * 8);
      g2l16(Bw + (size_t)(n0 + row) * K + k0 + cl * 8, Bs[buf] + (size_t)cbase * 8);
    }
  };

  stage(0, 0);
  for (int k0 = 0; k0 < K; k0 += 32) {
    __syncthreads();
    int cur = (k0 >> 5) & 1;
    if (k0 + 32 < K) stage(cur ^ 1, k0 + 32);

    short8 af[4], bfr[4];
#pragma unroll
    for (int mi = 0; mi < 4; ++mi)
      af[mi] = *(const short8*)(As[cur] + (wm*64 + mi*16 + l16)*32 + ((quad ^ swg) * 8));
#pragma unroll
    for (int ni = 0; ni < 4; ++ni)
      bfr[ni] = *(const short8*)(Bs[cur] + (wn*64 + ni*16 + l16)*32 + ((quad ^ swg) * 8));
#pragma unroll
    for (int mi = 0; mi < 4; ++mi)
#pragma unroll
      for (int ni = 0; ni < 4; ++ni)
        acc[mi][ni] = MFMA16(af[mi], bfr[ni], acc[mi][ni]);
  }

#pragma unroll
  for (int ni = 0; ni < 4; ++ni) {
    int n = n0 + wn*64 + ni*16 + l16;
    float bias = b0[n];
#pragma unroll
    for (int mi = 0; mi < 4; ++mi) {
#pragma unroll
      for (int r = 0; r < 4; ++r) {
        int m = m0 + wm*64 + mi*16 + quad*4 + r;
        Cout[(size_t)m * N + n] = acc[mi][ni][r] + bias;
      }
    }
  }
}

// Flash attention, causal, GQA, shift-free exp2 softmax. 32x32x16 MFMA.
// 4 waves x 32 q-rows = 128-row Q-tile; K/V tiles 128 keys in LDS (dbuf,
// 64KB -- free at the grid-capped 2 blocks/CU). P in-register via pkbf +
// permlane32_swap. 2-pass (qt,15-qt) for constant per-block work.
// Diagonal tile is exactly kt==qt: wave w skips fully-masked kb>w blocks.
// 32x32 C-layout: col = lane&31, row = (reg&3) + 8*(reg>>2) + 4*(lane>>5).
__global__ __launch_bounds__(256, 2)
void attn(const ushort* __restrict__ Q, const ushort* __restrict__ Kb,
          const ushort* __restrict__ Vt, ushort* __restrict__ Y) {
  __shared__ ushort Ks[2][128*64];   // [buf][key][d]
  __shared__ ushort Vs[2][64*128];   // [buf][d][key]
  const int tid = threadIdx.x, wave = tid >> 6, lane = tid & 63;
  const int l32 = lane & 31, hh = lane >> 5;
  const int h = blockIdx.y, b = blockIdx.z;
  const int hk = h >> 2;
  const ushort* Qb = Q  + ((size_t)(b*32 + h)  * 2048) * 64;
  const ushort* Kg = Kb + ((size_t)(b*8 + hk) * 2048) * 64;
  const ushort* Vg = Vt + ((size_t)(b*8 + hk) * 64) * 2048;

  // stage one 128x64 K tile + one 64x128 V tile; chunk-XOR swizzle on the
  // global source (LDS dest linear per global_load_lds rules)
  auto stage = [&](int buf, int kt) {
#pragma unroll
    for (int i = 0; i < 4; ++i) {
      int p = i*256 + tid;               // 0..1023 16B chunks
      int krow = p >> 3, kcb = p & 7;    // K: row stride 8 chunks
      int kcl = kcb ^ (krow & 7);
      g2l16(Kg + (size_t)(kt*128 + krow)*64 + kcl*8, Ks[buf] + (size_t)p*8);
      int vrow = p >> 4, vcb = p & 15;   // V: row stride 16 chunks
      int vcl = vcb ^ (vrow & 15);
      g2l16(Vg + (size_t)vrow*2048 + kt*128 + vcl*8, Vs[buf] + (size_t)p*8);
    }
  };

  for (int pass = 0; pass < 2; ++pass) {
    const int qt = pass ? (15 - blockIdx.x) : blockIdx.x;   // pair (qt, 15-qt)
    const int q0 = qt * 128;
    const int qrow = q0 + wave*32 + l32;
    // Q B-frags: for kstep ks, lane holds col q=qrow, d = ks*16 + hh*8 + j
    short8 qf[4];
#pragma unroll
    for (int ks = 0; ks < 4; ++ks)
      qf[ks] = *(const short8*)(Qb + (size_t)qrow*64 + ks*16 + hh*8);

    f32x16 o[2] = {};     // O^T: rows d, col q
    float lsum = 0.f;

    __syncthreads();            // LDS reuse across passes
    stage(0, 0);

    for (int kt = 0; kt <= qt; ++kt) {
      __syncthreads();          // drain = prefetch issued one tile ago
      int cur = kt & 1;
      if (kt < qt) stage(cur ^ 1, kt + 1);

      const ushort* Kl = Ks[cur];
      const ushort* Vl = Vs[cur];
      const bool diag = (kt == qt);

#pragma unroll
      for (int kb = 0; kb < 4; ++kb) {
        if (diag && kb > wave) continue;   // fully-masked 32-key block

        // S^T = K Q^T for this 32-key block, K=64 over 4 ksteps
        f32x16 s = {};
        __builtin_amdgcn_s_setprio(1);
#pragma unroll
        for (int ks = 0; ks < 4; ++ks) {
          int row = kb*32 + l32;
          short8 kf = *(const short8*)(Kl + row*64 + (((ks*2 + hh) ^ (row & 7)) * 8));
          s = MFMA32(kf, qf[ks], s);
        }
        __builtin_amdgcn_s_setprio(0);

        // causal mask: only the diagonal 32x32 block needs per-lane masking
        if (diag && kb == wave) {
#pragma unroll
          for (int r = 0; r < 16; ++r) {
            int key = kt*128 + kb*32 + (r & 3) + 8*(r >> 2) + 4*hh;
            if (key > qrow) s[r] = -INFINITY;
          }
        }

        // shift-free: p = exp2(s); exp2(-inf)=0 handles the mask
#pragma unroll
        for (int r = 0; r < 16; ++r) {
          s[r] = __builtin_amdgcn_exp2f(s[r]);
          lsum += s[r];
        }

        // P -> bf16 B-frags in-register, then PV for this 32-key block
        __builtin_amdgcn_s_setprio(1);
#pragma unroll
        for (int c = 0; c < 2; ++c) {
          int rb = c*8;
          uint a0 = pkbf(s[rb+0], s[rb+1]);
          uint b0 = pkbf(s[rb+4], s[rb+5]);
          uint a1 = pkbf(s[rb+2], s[rb+3]);
          uint b1 = pkbf(s[rb+6], s[rb+7]);
          uint2v r0 = __builtin_amdgcn_permlane32_swap(a0, b0, false, false);
          uint2v r1 = __builtin_amdgcn_permlane32_swap(a1, b1, false, false);
          union { uint u[4]; short8 s8; } pa;
          pa.u[0] = r0[0]; pa.u[1] = r1[0]; pa.u[2] = r0[1]; pa.u[3] = r1[1];
          // O^T += V^T P^T; V chunk w = kb*4 + c*2 + hh of 16 per d-row
#pragma unroll
          for (int db = 0; db < 2; ++db) {
            int row = db*32 + l32;
            int w = kb*4 + c*2 + hh;
            short8 vf = *(const short8*)(Vl + row*128 + ((w ^ (row & 15)) * 8));
            o[db] = MFMA32(vf, pa.s8, o[db]);
          }
        }
        __builtin_amdgcn_s_setprio(0);
      }
    }

    // combine denominator across lane halves (lanes l and l^32 share q-col)
    union { float f; uint u; } lu; lu.f = lsum;
    uint2v lr = __builtin_amdgcn_permlane32_swap(lu.u, lu.u, false, false);
    union { uint u; float f; } la, lb; la.u = lr[0]; lb.u = lr[1];
    float inv = 1.0f / (la.f + lb.f);

    // write Y[b][q][h*64 + d]: per db, 4 runs of 4 consecutive d
#pragma unroll
    for (int db = 0; db < 2; ++db) {
#pragma unroll
      for (int g = 0; g < 4; ++g) {
        int d = db*32 + 8*g + 4*hh;
        size_t base = ((size_t)(b*2048 + qrow)) * 2048 + h*64 + d;
        uint2 pk;
        pk.x = pkbf(o[db][4*g+0]*inv, o[db][4*g+1]*inv);
        pk.y = pkbf(o[db][4*g+2]*inv, o[db][4*g+3]*inv);
        *(uint2*)((ushort*)Y + base) = pk;
      }
    }
  }
}

extern "C" void kernel_launch(void* const* d_in, const int* in_sizes, int n_in,
                              void* d_out, int out_size, void* d_ws, size_t ws_size,
                              hipStream_t stream) {
  (void)in_sizes; (void)n_in; (void)out_size; (void)ws_size;
  const float* x  = (const float*)d_in[0];
  const float* Wq = (const float*)d_in[1];
  const float* bq = (const float*)d_in[2];
  const float* Wk = (const float*)d_in[3];
  const float* bk = (const float*)d_in[4];
  const float* Wv = (const float*)d_in[5];
  const float* bv = (const float*)d_in[6];
  const float* Wo = (const float*)d_in[7];
  const float* bo = (const float*)d_in[8];
  float* out = (float*)d_out;

  ushort* ws    = (ushort*)d_ws;
  ushort* x_bf  = ws;                        // 8388608
  ushort* wqkv  = x_bf + 8388608;            // 6291456  [3072][2048]
  ushort* wo_bf = wqkv + 6291456;            // 4194304
  ushort* qr    = wo_bf + 4194304;           // 8388608  [2][32][2048][64]
  ushort* kr    = qr + 8388608;              // 2097152  [2][8][2048][64]
  ushort* vt    = kr + 2097152;              // 2097152  [2][8][64][2048]
  ushort* Y     = x_bf;                      // x_bf dead after gemm_qkv

  cvt_all<<<18432, 256, 0, stream>>>(x, Wq, Wk, Wv, Wo, x_bf, wqkv, wo_bf);
  gemm_qkv<<<dim3(24, 32), 256, 0, stream>>>(x_bf, wqkv, bq, bk, bv, qr, kr, vt);
  attn<<<dim3(8, 32, 2), 256, 0, stream>>>(qr, kr, vt, Y);
  gemm128<<<dim3(16, 32), 256, 0, stream>>>(Y, wo_bf, bo, out, 4096, 2048, 2048);
}